// Round 1
// 443.522 us; speedup vs baseline: 1.1318x; 1.1318x over previous
//
#include <hip/hip_runtime.h>
#include <hip/hip_bf16.h>

// Problem constants (B=64, S=2048, H=512)
#define BATCH 64
#define SEQ   2048
#define HID   512
#define ROWS  (BATCH * SEQ)   // 131072

typedef __attribute__((ext_vector_type(8))) short short8;
typedef __attribute__((ext_vector_type(4))) float f32x4;

#define GLOBAL_AS __attribute__((address_space(1)))
#define LDS_AS    __attribute__((address_space(3)))

__device__ __forceinline__ void g2l16(const void* g, void* l) {
    __builtin_amdgcn_global_load_lds((const GLOBAL_AS unsigned int*)g,
                                     (LDS_AS unsigned int*)l, 16, 0, 0);
}

__device__ inline unsigned int cvt2_bf16(float x, float y) {
    __hip_bfloat162 h = __float22bfloat162_rn(make_float2(x, y));
    union { __hip_bfloat162 h2; unsigned int u; } u;
    u.h2 = h;
    return u.u;
}

__device__ inline float fast_tanh(float x) {
    float e = __expf(2.0f * x);
    return 1.0f - 2.0f / (e + 1.0f);
}

// ---------- k_prep2: cvt attw[:, :H] -> bf16 wb, plus fin-projection cbuf ----------
// grid 1152: bid<128 -> wb convert (2 MB read), else fin GEMV (tiny)
__global__ void k_prep2(const float* __restrict__ attw, const float* __restrict__ attb,
                        const float* __restrict__ fin, unsigned short* __restrict__ wb,
                        float* __restrict__ cbuf) {
    int bid = blockIdx.x;
    int t   = threadIdx.x;
    if (bid < 128) {
        size_t e = ((size_t)bid * 256 + t) * 8;   // [0, 262144)
        int k = (int)(e >> 9);
        int h = (int)(e & 511);
        const float* g = attw + (size_t)k * (2 * HID) + h;
        float4 a0 = *(const float4*)g;
        float4 a1 = *(const float4*)(g + 4);
        uint4 p = {cvt2_bf16(a0.x, a0.y), cvt2_bf16(a0.z, a0.w),
                   cvt2_bf16(a1.x, a1.y), cvt2_bf16(a1.z, a1.w)};
        *(uint4*)(wb + (size_t)k * HID + h) = p;
    } else {
        int fb = bid - 128;                 // [0, 1024)
        int b  = fb >> 4;
        int k  = (fb & 15) * 32 + (t >> 3);
        int l8 = t & 7;
        const float* f = fin + b * HID;
        const float* w = attw + (size_t)k * (2 * HID) + HID;
        float s = 0.0f;
        for (int h = l8 * 4; h < HID; h += 32) {
            float4 a  = *(const float4*)(f + h);
            float4 ww = *(const float4*)(w + h);
            s += a.x * ww.x + a.y * ww.y + a.z * ww.z + a.w * ww.w;
        }
        s += __shfl_xor(s, 1);
        s += __shfl_xor(s, 2);
        s += __shfl_xor(s, 4);
        if (l8 == 0) cbuf[b * HID + k] = s + attb[k];
    }
}

// ---------- k_energy_f: fused cvt + full-N GEMM + tanh·v + block softmax + partial context ----------
// grid 2048 × 256 threads. Block = 64 enc rows × all 512 output cols.
// Reads enc fp32 ONCE for the GEMM (reg-staged cvt→LDS), B via g2l16 from bf16 wb (L2-resident),
// then block-local softmax over its 64 scores and a partial numerator from L2-warm enc rows.
__global__ __launch_bounds__(256, 2) void k_energy_f(
        const float* __restrict__ enc, const unsigned short* __restrict__ wb,
        const float* __restrict__ cbuf, const float* __restrict__ vw,
        float* __restrict__ num, float* __restrict__ ml) {
    __shared__ __align__(16) unsigned short As[64 * 64];    // 8 KB
    __shared__ __align__(16) unsigned short Bs[512 * 64];   // 64 KB  (72 KB total -> 2 blocks/CU)

    const int sRow = blockIdx.x * 64;
    const int bIdx = sRow >> 11;         // 64-row blocks never straddle a batch
    const int t    = threadIdx.x;
    const int lane = t & 63;
    const int wave = t >> 6;             // 0..3 -> col quarter (128 cols each)
    const int l16  = lane & 15;
    const int q    = lane >> 4;

    // A staging: thread t owns row tr, 16 fp32 cols starting at tc
    const int tr = t >> 2;               // 0..63
    const int tc = (t & 3) * 16;
    const int c0 = (t & 3) * 2;          // 16B-chunk pair index

    // B staging (g2l16, linear dest + pre-swizzled source)
    const int lr  = lane >> 3;
    const int lc  = lane & 7;
    const int swz = lc ^ lr;

    const float* gA = enc + (size_t)(sRow + tr) * HID + tc;
    const unsigned short* gB = wb + (size_t)(wave * 128 + lr) * HID + swz * 8;

    f32x4 acc[4][8];
    #pragma unroll
    for (int i = 0; i < 4; ++i)
        #pragma unroll
        for (int j = 0; j < 8; ++j) acc[i][j] = (f32x4){0.f, 0.f, 0.f, 0.f};

    for (int h0 = 0; h0 < HID; h0 += 64) {
        // issue A fp32 loads first so their waitcnt doesn't drain the g2l16 queue
        float4 a0 = *(const float4*)(gA + h0);
        float4 a1 = *(const float4*)(gA + h0 + 4);
        float4 a2 = *(const float4*)(gA + h0 + 8);
        float4 a3 = *(const float4*)(gA + h0 + 12);
        #pragma unroll
        for (int j = 0; j < 16; ++j)
            g2l16(gB + (size_t)(j * 8) * HID + h0, Bs + (wave * 128 + j * 8) * 64);
        uint4 p0 = {cvt2_bf16(a0.x, a0.y), cvt2_bf16(a0.z, a0.w),
                    cvt2_bf16(a1.x, a1.y), cvt2_bf16(a1.z, a1.w)};
        uint4 p1 = {cvt2_bf16(a2.x, a2.y), cvt2_bf16(a2.z, a2.w),
                    cvt2_bf16(a3.x, a3.y), cvt2_bf16(a3.z, a3.w)};
        *(uint4*)(&As[tr * 64 + ((c0    ) ^ (tr & 7)) * 8]) = p0;
        *(uint4*)(&As[tr * 64 + ((c0 + 1) ^ (tr & 7)) * 8]) = p1;
        __syncthreads();

        #pragma unroll
        for (int kk = 0; kk < 64; kk += 32) {
            short8 af[4], bf[8];
            const int cb = (kk >> 3) + q;
            #pragma unroll
            for (int i = 0; i < 4; ++i) {
                int row = i * 16 + l16;
                af[i] = *(const short8*)(&As[row * 64 + (cb ^ (row & 7)) * 8]);
            }
            #pragma unroll
            for (int j = 0; j < 8; ++j) {
                int row = wave * 128 + j * 16 + l16;
                bf[j] = *(const short8*)(&Bs[row * 64 + (cb ^ (row & 7)) * 8]);
            }
            #pragma unroll
            for (int i = 0; i < 4; ++i)
                #pragma unroll
                for (int j = 0; j < 8; ++j)
                    acc[i][j] = __builtin_amdgcn_mfma_f32_16x16x32_bf16(
                        af[i], bf[j], acc[i][j], 0, 0, 0);
        }
        __syncthreads();
    }

    // ---- scores: tanh(e + c)·v reduced over all 512 cols ----
    float* ssc = (float*)As;             // As is dead now; reuse
    float* wsm = (float*)As + 64;

    if (t < 64) ssc[t] = 0.0f;
    __syncthreads();

    float cv[8], vv[8];
    #pragma unroll
    for (int j = 0; j < 8; ++j) {
        int c = wave * 128 + j * 16 + l16;
        cv[j] = cbuf[bIdx * HID + c];
        vv[j] = vw[c];
    }

    // C/D mapping: col = lane&15, row = q*4 + reg
    #pragma unroll
    for (int i = 0; i < 4; ++i) {
        #pragma unroll
        for (int r = 0; r < 4; ++r) {
            float sum = 0.0f;
            #pragma unroll
            for (int j = 0; j < 8; ++j)
                sum += fast_tanh(acc[i][j][r] + cv[j]) * vv[j];
            sum += __shfl_xor(sum, 1);
            sum += __shfl_xor(sum, 2);
            sum += __shfl_xor(sum, 4);
            sum += __shfl_xor(sum, 8);
            if (l16 == 0) atomicAdd(&ssc[i * 16 + q * 4 + r], sum);
        }
    }
    __syncthreads();

    // ---- block-local softmax over the 64 rows (flash-style partial) ----
    if (t < 64) {
        float x  = ssc[t];
        float mx = x;
        #pragma unroll
        for (int m = 1; m < 64; m <<= 1) mx = fmaxf(mx, __shfl_xor(mx, m));
        float p = __expf(x - mx);
        float l = p;
        #pragma unroll
        for (int m = 1; m < 64; m <<= 1) l += __shfl_xor(l, m);
        wsm[t] = p;
        if (t == 0) ((float2*)ml)[blockIdx.x] = make_float2(mx, l);
    }
    __syncthreads();

    // ---- partial numerator: num = Σ_s p_s · enc[s,:]  (fp32, rows are L2-warm) ----
    const float* e2 = enc + (size_t)sRow * HID + t * 2;
    float ax = 0.0f, ay = 0.0f;
    #pragma unroll 8
    for (int s = 0; s < 64; ++s) {
        float p  = wsm[s];
        float2 v = *(const float2*)(e2 + (size_t)s * HID);
        ax += p * v.x;
        ay += p * v.y;
    }
    *(float2*)(num + (size_t)blockIdx.x * HID + t * 2) = make_float2(ax, ay);
}

// ---------- k_combine: merge 32 block partials per batch, write out exactly ----------
__global__ void k_combine(const float* __restrict__ num, const float* __restrict__ ml,
                          float* __restrict__ out) {
    int b = blockIdx.x;
    int t = threadIdx.x;
    __shared__ float sm[32], sl[32], sc[32];
    __shared__ float sM;
    if (t < 32) {
        float2 v = ((const float2*)ml)[b * 32 + t];
        sm[t] = v.x;
        sl[t] = v.y;
    }
    __syncthreads();
    if (t == 0) {
        float M = -1e30f;
        for (int i = 0; i < 32; ++i) M = fmaxf(M, sm[i]);
        sM = M;
    }
    __syncthreads();
    if (t < 32) sc[t] = __expf(sm[t] - sM);
    __syncthreads();
    float L = 0.0f;
    #pragma unroll
    for (int i = 0; i < 32; ++i) L += sc[i] * sl[i];
    float inv = 1.0f / L;
    const float* n = num + (size_t)b * 32 * HID + t;
    float a0 = 0.0f, a1 = 0.0f;
    #pragma unroll
    for (int i = 0; i < 32; ++i) {
        a0 += sc[i] * n[(size_t)i * HID];
        a1 += sc[i] * n[(size_t)i * HID + 256];
    }
    out[b * HID + t]       = a0 * inv;
    out[b * HID + t + 256] = a1 * inv;
}

// ================= fallback path (fp32 in-kernel cvt, small ws) =================
#define BK  64
#define LDA 72

__global__ __launch_bounds__(256) void k_energy_fb(
        const float* __restrict__ enc, const float* __restrict__ attw,
        const float* __restrict__ cbuf, const float* __restrict__ vw,
        float* __restrict__ scores) {
    __shared__ __align__(16) unsigned short As[128 * LDA];
    __shared__ __align__(16) unsigned short Bs[128 * LDA];
    const int nTile = blockIdx.x * 128;
    const int sRow  = blockIdx.y * 128;
    const int bIdx  = sRow >> 11;
    const int t = threadIdx.x, lane = t & 63, wave = t >> 6;
    const int wm = wave >> 1, wn = wave & 1, l16 = lane & 15, q = lane >> 4;
    const int tr = t >> 3, tc = (t & 7) * 8;

    f32x4 acc[4][4];
    #pragma unroll
    for (int i = 0; i < 4; ++i)
        #pragma unroll
        for (int j = 0; j < 4; ++j) acc[i][j] = (f32x4){0.f, 0.f, 0.f, 0.f};

    for (int h0 = 0; h0 < HID; h0 += BK) {
        #pragma unroll
        for (int i = 0; i < 4; ++i) {
            int row = tr + i * 32;
            const float* gA = enc + (size_t)(sRow + row) * HID + h0 + tc;
            float4 a0 = *(const float4*)gA;
            float4 a1 = *(const float4*)(gA + 4);
            uint4 pa = {cvt2_bf16(a0.x, a0.y), cvt2_bf16(a0.z, a0.w),
                        cvt2_bf16(a1.x, a1.y), cvt2_bf16(a1.z, a1.w)};
            *(uint4*)(&As[row * LDA + tc]) = pa;
            const float* gB = attw + (size_t)(nTile + row) * (2 * HID) + h0 + tc;
            float4 b0 = *(const float4*)gB;
            float4 b1 = *(const float4*)(gB + 4);
            uint4 pb = {cvt2_bf16(b0.x, b0.y), cvt2_bf16(b0.z, b0.w),
                        cvt2_bf16(b1.x, b1.y), cvt2_bf16(b1.z, b1.w)};
            *(uint4*)(&Bs[row * LDA + tc]) = pb;
        }
        __syncthreads();
        #pragma unroll
        for (int kk = 0; kk < BK; kk += 32) {
            short8 af[4], bf[4];
            #pragma unroll
            for (int i = 0; i < 4; ++i)
                af[i] = *(const short8*)(&As[(wm * 64 + i * 16 + l16) * LDA + kk + q * 8]);
            #pragma unroll
            for (int j = 0; j < 4; ++j)
                bf[j] = *(const short8*)(&Bs[(wn * 64 + j * 16 + l16) * LDA + kk + q * 8]);
            #pragma unroll
            for (int i = 0; i < 4; ++i)
                #pragma unroll
                for (int j = 0; j < 4; ++j)
                    acc[i][j] = __builtin_amdgcn_mfma_f32_16x16x32_bf16(
                        af[i], bf[j], acc[i][j], 0, 0, 0);
        }
        __syncthreads();
    }
    #pragma unroll
    for (int i = 0; i < 4; ++i) {
        #pragma unroll
        for (int r = 0; r < 4; ++r) {
            float sum = 0.0f;
            #pragma unroll
            for (int j = 0; j < 4; ++j) {
                int colg = nTile + wn * 64 + j * 16 + l16;
                sum += fast_tanh(acc[i][j][r] + cbuf[bIdx * HID + colg]) * vw[colg];
            }
            sum += __shfl_xor(sum, 1);
            sum += __shfl_xor(sum, 2);
            sum += __shfl_xor(sum, 4);
            sum += __shfl_xor(sum, 8);
            if (l16 == 0) atomicAdd(&scores[sRow + wm * 64 + i * 16 + q * 4 + r], sum);
        }
    }
}

__global__ void k_softmax(float* __restrict__ sw) {
    int b = blockIdx.x;
    float* s = sw + (size_t)b * SEQ;
    int t = threadIdx.x;
    __shared__ float red[4];
    float lmax = -1e30f;
    for (int i = t; i < SEQ; i += 256) lmax = fmaxf(lmax, s[i]);
    for (int m = 1; m < 64; m <<= 1) lmax = fmaxf(lmax, __shfl_xor(lmax, m));
    if ((t & 63) == 0) red[t >> 6] = lmax;
    __syncthreads();
    float gmax = fmaxf(fmaxf(red[0], red[1]), fmaxf(red[2], red[3]));
    __syncthreads();
    float lsum = 0.0f;
    for (int i = t; i < SEQ; i += 256) lsum += __expf(s[i] - gmax);
    for (int m = 1; m < 64; m <<= 1) lsum += __shfl_xor(lsum, m);
    if ((t & 63) == 0) red[t >> 6] = lsum;
    __syncthreads();
    float inv = 1.0f / (red[0] + red[1] + red[2] + red[3]);
    for (int i = t; i < SEQ; i += 256) s[i] = __expf(s[i] - gmax) * inv;
}

__global__ void k_fin_fb(const float* __restrict__ fin, const float* __restrict__ attw,
                         const float* __restrict__ attb, float* __restrict__ cbuf) {
    int b  = blockIdx.y;
    int k  = blockIdx.x * 32 + (threadIdx.x >> 3);
    int l8 = threadIdx.x & 7;
    const float* f = fin + b * HID;
    const float* w = attw + (size_t)k * (2 * HID) + HID;
    float s = 0.0f;
    for (int h = l8 * 4; h < HID; h += 32) {
        float4 a  = *(const float4*)(f + h);
        float4 ww = *(const float4*)(w + h);
        s += a.x * ww.x + a.y * ww.y + a.z * ww.z + a.w * ww.w;
    }
    s += __shfl_xor(s, 1);
    s += __shfl_xor(s, 2);
    s += __shfl_xor(s, 4);
    if (l8 == 0) cbuf[b * HID + k] = s + attb[k];
}

__global__ void k_context_fb(const float* __restrict__ enc, const float* __restrict__ wts,
                             float* __restrict__ out) {
    int b = blockIdx.y, sc = blockIdx.x, t = threadIdx.x;
    const float* e = enc + ((size_t)b * SEQ + sc * 128) * HID + t * 2;
    const float* w = wts + (size_t)b * SEQ + sc * 128;
    float ax = 0.f, ay = 0.f;
    #pragma unroll 4
    for (int s = 0; s < 128; ++s) {
        float ws = w[s];
        float2 v = *(const float2*)(e + (size_t)s * HID);
        ax += ws * v.x;
        ay += ws * v.y;
    }
    atomicAdd(&out[b * HID + t * 2], ax);
    atomicAdd(&out[b * HID + t * 2 + 1], ay);
}

extern "C" void kernel_launch(void* const* d_in, const int* in_sizes, int n_in,
                              void* d_out, int out_size, void* d_ws, size_t ws_size,
                              hipStream_t stream) {
    const float* enc  = (const float*)d_in[0];
    const float* fin  = (const float*)d_in[1];
    const float* attw = (const float*)d_in[2];
    const float* attb = (const float*)d_in[3];
    const float* vw   = (const float*)d_in[4];
    float* out = (float*)d_out;

    char* ws = (char*)d_ws;
    float* cbuf        = (float*)ws;                                     // 131072 B
    unsigned short* wb = (unsigned short*)(ws + 131072);                 // 524288 B
    float* num         = (float*)(ws + 131072 + 524288);                 // 4194304 B
    float* mlb         = (float*)(ws + 131072 + 524288 + 4194304);       // 16384 B
    const size_t need = 131072ull + 524288 + 4194304 + 16384;

    if (ws_size >= need) {
        k_prep2<<<1152, 256, 0, stream>>>(attw, attb, fin, wb, cbuf);
        k_energy_f<<<ROWS / 64, 256, 0, stream>>>(enc, wb, cbuf, vw, num, mlb);
        k_combine<<<BATCH, 256, 0, stream>>>(num, mlb, out);
    } else {
        float* sp = (float*)(ws + 131072);
        hipMemsetAsync(out, 0, (size_t)BATCH * HID * sizeof(float), stream);
        hipMemsetAsync(sp, 0, (size_t)ROWS * sizeof(float), stream);
        k_fin_fb<<<dim3(16, 64), 256, 0, stream>>>(fin, attw, attb, cbuf);
        k_energy_fb<<<dim3(4, ROWS / 128), 256, 0, stream>>>(enc, attw, cbuf, vw, sp);
        k_softmax<<<BATCH, 256, 0, stream>>>(sp);
        k_context_fb<<<dim3(16, 64), 256, 0, stream>>>(enc, sp, out);
    }
}